// Round 11
// baseline (321.392 us; speedup 1.0000x reference)
//
#include <hip/hip_runtime.h>
#include <math.h>

#define NEG_SLOPE 0.2f

__device__ inline float lrelu(float x) { return x > 0.f ? x : NEG_SLOPE * x; }

typedef __attribute__((ext_vector_type(8))) _Float16 f16x8;
typedef __attribute__((ext_vector_type(4))) float f32x4;
typedef __attribute__((ext_vector_type(2))) float f32x2;
typedef __attribute__((ext_vector_type(4))) _Float16 h16x4;

// Convert W1[K1,N1], W2[K2,N2] fp32 -> BT [N][K] fp16 (transposed)
__global__ void convW_k(const float* __restrict__ W1, const float* __restrict__ W2,
                        _Float16* __restrict__ BT1, _Float16* __restrict__ BT2)
{
    int i = blockIdx.x * blockDim.x + threadIdx.x;   // 65536 total
    if (i < 32768) {
        int n = i >> 7, k = i & 127;                 // K=128, N=256
        BT1[(size_t)n * 128 + k] = (_Float16)W1[(size_t)k * 256 + n];
    } else {
        int idx = i - 32768;
        int n = idx >> 8, k = idx & 255;             // K=256, N=128
        BT2[(size_t)n * 256 + k] = (_Float16)W2[(size_t)k * 128 + n];
    }
}

// ---- Fused fp16 MFMA GEMM + fp8 out + attention logits -----------------------
// C = A[M,K] @ W[K,N] (fp16 compute, fp32 acc); epilogue writes HB (fp8 e4m3)
// and per-row attn logits aS/aD. H=4: direct store head=wave; H=1: cross-wave
// LDS reduction then direct store (no atomics, no pre-zeroed buffers).
template<int N, int K, int H, bool AF16>
__launch_bounds__(256)
__global__ void gemm_fused(const void* __restrict__ A, const _Float16* __restrict__ BT,
                           unsigned char* __restrict__ HB, const float* __restrict__ att_s,
                           const float* __restrict__ att_d, float* __restrict__ aS,
                           float* __restrict__ aD, int M)
{
    constexpr int ITERS = K / 32;
    constexpr int WN = N / 4;
    constexpr int NT = WN / 16;
    constexpr int NCH = (N * 4) / 256;
    __shared__ unsigned short As[64 * 40] __attribute__((aligned(16)));
    __shared__ unsigned short Bs[N * 40] __attribute__((aligned(16)));
    __shared__ float sred[2][4][64];               // H==1 cross-wave logit reduce
    const int t = threadIdx.x;
    const int wave = t >> 6, lane = t & 63;
    const int quad = lane >> 4, l15 = lane & 15;
    const int rowBase = blockIdx.x * 64;

    f32x4 acc[4][NT];
#pragma unroll
    for (int mi = 0; mi < 4; ++mi)
#pragma unroll
        for (int ni = 0; ni < NT; ++ni)
            acc[mi][ni] = (f32x4){0.f, 0.f, 0.f, 0.f};

    const int ar = t >> 2;             // A-stage row 0..63
    const int ak = (t & 3) << 3;       // A-stage k seg 0,8,16,24
    const int bc = (t * NCH) >> 2;     // B-stage column
    const int bks = (t * NCH) & 3;     // B-stage starting chunk

    for (int it = 0; it < ITERS; ++it) {
        // ---- stage A
        {
            int gr = rowBase + ar;
            f16x8 hv;
#pragma unroll
            for (int j = 0; j < 8; ++j) hv[j] = (_Float16)0.f;
            if (gr < M) {
                if constexpr (AF16) {
                    hv = *(const f16x8*)((const _Float16*)A + (size_t)gr * K + it * 32 + ak);
                } else {
                    const float* ap = (const float*)A + (size_t)gr * K + it * 32 + ak;
                    float4 v0 = *(const float4*)ap;
                    float4 v1 = *(const float4*)(ap + 4);
                    hv[0] = (_Float16)v0.x; hv[1] = (_Float16)v0.y;
                    hv[2] = (_Float16)v0.z; hv[3] = (_Float16)v0.w;
                    hv[4] = (_Float16)v1.x; hv[5] = (_Float16)v1.y;
                    hv[6] = (_Float16)v1.z; hv[7] = (_Float16)v1.w;
                }
            }
            *(f16x8*)&As[ar * 40 + ak] = hv;
        }
        // ---- stage B (pre-converted fp16, contiguous copy)
        {
            const _Float16* bp = BT + (size_t)bc * K + it * 32 + bks * 8;
            unsigned short* dp = &Bs[bc * 40 + bks * 8];
#pragma unroll
            for (int j = 0; j < NCH; ++j)
                *(f16x8*)(dp + j * 8) = *(const f16x8*)(bp + j * 8);
        }
        __syncthreads();
        f16x8 af[4], bfr[NT];
#pragma unroll
        for (int mi = 0; mi < 4; ++mi)
            af[mi] = *(const f16x8*)&As[(mi * 16 + l15) * 40 + quad * 8];
#pragma unroll
        for (int ni = 0; ni < NT; ++ni)
            bfr[ni] = *(const f16x8*)&Bs[(wave * WN + ni * 16 + l15) * 40 + quad * 8];
#pragma unroll
        for (int mi = 0; mi < 4; ++mi)
#pragma unroll
            for (int ni = 0; ni < NT; ++ni)
                acc[mi][ni] = __builtin_amdgcn_mfma_f32_16x16x32_f16(
                    af[mi], bfr[ni], acc[mi][ni], 0, 0, 0);
        __syncthreads();
    }
    // ---- epilogue: fp8 store + logits. D layout col=lane&15, row=quad*4+reg
    float asv[NT], adv[NT];
#pragma unroll
    for (int ni = 0; ni < NT; ++ni) {
        int col = wave * WN + ni * 16 + l15;
        asv[ni] = att_s[col];
        adv[ni] = att_d[col];
    }
#pragma unroll
    for (int mi = 0; mi < 4; ++mi) {
#pragma unroll
        for (int r = 0; r < 4; ++r) {
            int row = rowBase + mi * 16 + quad * 4 + r;
            bool ok = row < M;
            float ss = 0.f, sd = 0.f;
#pragma unroll
            for (int ni = 0; ni < NT; ++ni) {
                float v = acc[mi][ni][r];
                ss += v * asv[ni];
                sd += v * adv[ni];
            }
            // fp8 pack: 2 cols per cvt inst (cols are 16 apart -> byte stores)
#pragma unroll
            for (int ni = 0; ni < NT; ni += 2) {
                int pk = __builtin_amdgcn_cvt_pk_fp8_f32(acc[mi][ni][r],
                                                         acc[mi][ni + 1][r], 0, false);
                if (ok) {
                    HB[(size_t)row * N + wave * WN + ni * 16 + l15] =
                        (unsigned char)(pk & 0xff);
                    HB[(size_t)row * N + wave * WN + (ni + 1) * 16 + l15] =
                        (unsigned char)((pk >> 8) & 0xff);
                }
            }
#pragma unroll
            for (int off = 8; off > 0; off >>= 1) {
                ss += __shfl_xor(ss, off);
                sd += __shfl_xor(sd, off);
            }
            if (l15 == 0) {
                if (H == 4) {
                    if (ok) {
                        aS[row * 4 + wave] = ss;
                        aD[row * 4 + wave] = sd;
                    }
                } else {
                    sred[0][wave][mi * 16 + quad * 4 + r] = ss;
                    sred[1][wave][mi * 16 + quad * 4 + r] = sd;
                }
            }
        }
    }
    if (H == 1) {
        __syncthreads();
        if (t < 64) {
            int row = rowBase + t;
            if (row < M) {
                aS[row] = sred[0][0][t] + sred[0][1][t] + sred[0][2][t] + sred[0][3][t];
                aD[row] = sred[1][0][t] + sred[1][1][t] + sred[1][2][t] + sred[1][3][t];
            }
        }
    }
}

// =================== CSR build (two-phase sort, LDS-aggregated) =================
// phase 0: LDS-aggregated bucket counting (782 coarse buckets of 64 nodes).
#define BIN_EPT 32
__launch_bounds__(256)
__global__ void bcount_k(const int* __restrict__ dst, int* __restrict__ bcnt,
                         int ET, int E, int NBUCK)
{
    __shared__ int hist[1024];
    for (int i = threadIdx.x; i < NBUCK; i += 256) hist[i] = 0;
    __syncthreads();
    int e0 = blockIdx.x * (256 * BIN_EPT) + threadIdx.x;
#pragma unroll
    for (int j = 0; j < BIN_EPT; ++j) {
        int e = e0 + j * 256;
        if (e < ET) {
            int d = (e < E) ? dst[e] : (e - E);
            atomicAdd(&hist[d >> 6], 1);
        }
    }
    __syncthreads();
    for (int i = threadIdx.x; i < NBUCK; i += 256) {
        int c = hist[i];
        if (c > 0) atomicAdd(&bcnt[i], c);
    }
}

// phase 0b: single-block scan over buckets -> bucket bases + binpass cursors
__global__ void bscan_k(const int* __restrict__ bcnt, int* __restrict__ bbase,
                        int* __restrict__ ccursor, int nb)
{
    __shared__ int sh[1024];
    int t = threadIdx.x;
    int v = (t < nb) ? bcnt[t] : 0;
    sh[t] = v;
    __syncthreads();
#pragma unroll
    for (int o = 1; o < 1024; o <<= 1) {
        int u = (t >= o) ? sh[t - o] : 0;
        __syncthreads();
        sh[t] += u;
        __syncthreads();
    }
    if (t < nb) {
        int excl = sh[t] - v;
        bbase[t] = excl;
        ccursor[t] = excl;
    }
    if (t == nb - 1) bbase[nb] = sh[t];
}

// phase 1: LDS-aggregated coarse scatter. Each block: 8192 edges, LDS histogram,
// ONE global atomicAdd per (block,bucket), then ranked writes.
// Edge packs fully into u32: src | dst<<16 (both < 65536).
__launch_bounds__(256)
__global__ void binpass_k(const int* __restrict__ src, const int* __restrict__ dst,
                          int* __restrict__ ccursor, unsigned int* __restrict__ tmp,
                          int ET, int E, int NBUCK)
{
    __shared__ int hist[1024];
    for (int i = threadIdx.x; i < NBUCK; i += 256) hist[i] = 0;
    __syncthreads();
    int e0 = blockIdx.x * (256 * BIN_EPT) + threadIdx.x;
    unsigned int ev[BIN_EPT];
    int meta[BIN_EPT];
#pragma unroll
    for (int j = 0; j < BIN_EPT; ++j) {
        int e = e0 + j * 256;
        meta[j] = -1;
        if (e < ET) {
            int s, d;
            if (e < E) { s = src[e]; d = dst[e]; } else { s = e - E; d = s; }
            ev[j] = (unsigned int)s | ((unsigned int)d << 16);
            int b = d >> 6;
            int r = atomicAdd(&hist[b], 1);
            meta[j] = (r << 10) | b;          // rank<8192 (13b) | bucket (10b)
        }
    }
    __syncthreads();
    // reserve global ranges: one atomic per touched bucket per block
    for (int i = threadIdx.x; i < NBUCK; i += 256) {
        int c = hist[i];
        hist[i] = (c > 0) ? atomicAdd(&ccursor[i], c) : 0;
    }
    __syncthreads();
#pragma unroll
    for (int j = 0; j < BIN_EPT; ++j) {
        if (meta[j] >= 0) {
            int b = meta[j] & 1023;
            int r = meta[j] >> 10;
            tmp[hist[b] + r] = ev[j];
        }
    }
}

// phase 2: per-bucket fine placement. Derives per-node counts + rowptr from the
// bucket's own edges (64 LDS counters + LDS scan) -- no global count/scan pass.
__global__ void fine_k(const int* __restrict__ bbase, const unsigned int* __restrict__ tmp,
                       int* __restrict__ rowptr, unsigned short* __restrict__ esrc,
                       int Nn, int ET, int NBUCK)
{
    __shared__ int lcnt[64], lpre[64], lcur[64];
    int t = threadIdx.x;
    int b = blockIdx.x;
    int n0 = b << 6;
    int base = bbase[b];
    int end = bbase[b + 1];
    if (t < 64) lcnt[t] = 0;
    __syncthreads();
    for (int i = base + t; i < end; i += 256)
        atomicAdd(&lcnt[(tmp[i] >> 16) & 63], 1);
    __syncthreads();
    if (t < 64) lpre[t] = lcnt[t];
    __syncthreads();
#pragma unroll
    for (int o = 1; o < 64; o <<= 1) {
        int u = (t < 64 && t >= o) ? lpre[t - o] : 0;
        __syncthreads();
        if (t < 64) lpre[t] += u;
        __syncthreads();
    }
    if (t < 64) {
        int n = n0 + t;
        int excl = lpre[t] - lcnt[t];
        if (n < Nn) {
            rowptr[n] = base + excl;
            lcur[t] = base + excl;
        }
    }
    if (b == NBUCK - 1 && t == 0) rowptr[Nn] = ET;
    __syncthreads();
    for (int i = base + t; i < end; i += 256) {
        unsigned int v = tmp[i];
        int pos = atomicAdd(&lcur[(v >> 16) & 63], 1);
        esrc[pos] = (unsigned short)(v & 0xffffu);
    }
}

// ===== gather layer 1: fp8 h, zero-shift softmax, readlane edge broadcast ======
// One COALESCED load grabs up to 64 edge ids into lane registers; per-chunk
// wave-uniform s[j] come from v_readlane (register op, no memory) -- removes the
// esrc round-trip from the per-chunk critical path entirely.
__global__ void gather1_k(const int* __restrict__ rp, const unsigned short* __restrict__ esrc,
                          const unsigned char* __restrict__ hb, const float* __restrict__ aS,
                          const float* __restrict__ aD, const float* __restrict__ bias,
                          _Float16* __restrict__ out, int Nn)
{
    int d = blockIdx.x * 4 + (threadIdx.x >> 6);
    int lane = threadIdx.x & 63;
    if (d >= Nn) return;
    int c4 = lane << 2;                 // channel base = byte offset (fp8)
    int head = lane >> 4;
    int p0 = __builtin_amdgcn_readfirstlane(rp[d]);
    int p1 = __builtin_amdgcn_readfirstlane(rp[d + 1]);
    float adh = aD[d * 4 + head];
    const float* aSh = aS + head;
    float den = 0.f;
    float ax = 0.f, ay = 0.f, az = 0.f, aw = 0.f;
    for (int base = p0; base < p1; base += 64) {
        int idx = base + lane;
        int eid = (int)esrc[idx < p1 ? idx : p1 - 1];   // 1 coalesced load / 64 edges
        int navail = p1 - base;                         // uniform
        int nch = navail < 64 ? navail : 64;
        int fe = nch & ~7;                              // full chunks of 8
        for (int cb = 0; cb < fe; cb += 8) {
            int s[8];
#pragma unroll
            for (int j = 0; j < 8; ++j)
                s[j] = __builtin_amdgcn_readlane(eid, cb + j);
            unsigned int v[8];                          // issue vector loads early
#pragma unroll
            for (int j = 0; j < 8; ++j)
                v[j] = *(const unsigned int*)&hb[(size_t)s[j] * 256 + c4];
            float w[8];
#pragma unroll
            for (int j = 0; j < 8; ++j) w[j] = __expf(lrelu(aSh[s[j] * 4] + adh));
#pragma unroll
            for (int j = 0; j < 8; ++j) {
                den += w[j];
                f32x2 lo = __builtin_amdgcn_cvt_pk_f32_fp8((int)v[j], false);
                f32x2 hi = __builtin_amdgcn_cvt_pk_f32_fp8((int)v[j], true);
                ax += lo[0] * w[j];
                ay += lo[1] * w[j];
                az += hi[0] * w[j];
                aw += hi[1] * w[j];
            }
        }
        int rem = nch - fe;                             // 0..7, wave-uniform
        if (rem > 0) {
            int s[8];
            unsigned int v[8];
            float w[8];
#pragma unroll
            for (int j = 0; j < 8; ++j)
                s[j] = __builtin_amdgcn_readlane(eid, fe + j);  // clamped, safe
#pragma unroll
            for (int j = 0; j < 8; ++j)
                if (j < rem) v[j] = *(const unsigned int*)&hb[(size_t)s[j] * 256 + c4];
#pragma unroll
            for (int j = 0; j < 8; ++j)
                if (j < rem) w[j] = __expf(lrelu(aSh[s[j] * 4] + adh));
#pragma unroll
            for (int j = 0; j < 8; ++j) {
                if (j < rem) {
                    den += w[j];
                    f32x2 lo = __builtin_amdgcn_cvt_pk_f32_fp8((int)v[j], false);
                    f32x2 hi = __builtin_amdgcn_cvt_pk_f32_fp8((int)v[j], true);
                    ax += lo[0] * w[j];
                    ay += lo[1] * w[j];
                    az += hi[0] * w[j];
                    aw += hi[1] * w[j];
                }
            }
        }
    }
    float inv = 1.f / (den + 1e-16f);
    float4 b4 = *(const float4*)&bias[c4];
    float rx, ry, rz, rw;
    rx = ax * inv + b4.x; rx = rx > 0.f ? rx : expm1f(rx);
    ry = ay * inv + b4.y; ry = ry > 0.f ? ry : expm1f(ry);
    rz = az * inv + b4.z; rz = rz > 0.f ? rz : expm1f(rz);
    rw = aw * inv + b4.w; rw = rw > 0.f ? rw : expm1f(rw);
    h16x4 r16;
    r16[0] = (_Float16)rx; r16[1] = (_Float16)ry;
    r16[2] = (_Float16)rz; r16[3] = (_Float16)rw;
    *(h16x4*)&out[(size_t)d * 256 + c4] = r16;
}

// ===== gather layer 2 + fused mean-pool into PARTITIONED sums ==================
// readlane edge broadcast (as gather1) + zero-shift softmax + bias/ELU in-reg +
// block run-length accumulate + 32-way partitioned atomics (round-10 lesson).
__global__ void gather2_k(const int* __restrict__ rp, const unsigned short* __restrict__ esrc,
                          const unsigned char* __restrict__ hb, const float* __restrict__ aS,
                          const float* __restrict__ aD, const float* __restrict__ b2,
                          const int* __restrict__ batch, float* __restrict__ parts, int Nn)
{
    __shared__ float pv[4][128];
    __shared__ int pg[4];
    int wave = threadIdx.x >> 6;
    int d = blockIdx.x * 4 + wave;
    int lane = threadIdx.x & 63;
    int c2 = lane << 1;                 // channel base = byte offset (fp8)
    bool valid = d < Nn;
    if (lane == 0) pg[wave] = valid ? batch[d] : -1;
    if (valid) {
        int p0 = __builtin_amdgcn_readfirstlane(rp[d]);
        int p1 = __builtin_amdgcn_readfirstlane(rp[d + 1]);
        float adh = aD[d];
        float den = 0.f;
        float ax = 0.f, ay = 0.f;
        for (int base = p0; base < p1; base += 64) {
            int idx = base + lane;
            int eid = (int)esrc[idx < p1 ? idx : p1 - 1];
            int navail = p1 - base;
            int nch = navail < 64 ? navail : 64;
            int fe = nch & ~7;
            for (int cb = 0; cb < fe; cb += 8) {
                int s[8];
#pragma unroll
                for (int j = 0; j < 8; ++j)
                    s[j] = __builtin_amdgcn_readlane(eid, cb + j);
                unsigned short v[8];               // issue vector loads early
#pragma unroll
                for (int j = 0; j < 8; ++j)
                    v[j] = *(const unsigned short*)&hb[(size_t)s[j] * 128 + c2];
                float w[8];
#pragma unroll
                for (int j = 0; j < 8; ++j) w[j] = __expf(lrelu(aS[s[j]] + adh));
#pragma unroll
                for (int j = 0; j < 8; ++j) {
                    den += w[j];
                    f32x2 lo = __builtin_amdgcn_cvt_pk_f32_fp8((int)v[j], false);
                    ax += lo[0] * w[j];
                    ay += lo[1] * w[j];
                }
            }
            int rem = nch - fe;                      // 0..7, wave-uniform
            if (rem > 0) {
                int s[8];
                unsigned short v[8];
                float w[8];
#pragma unroll
                for (int j = 0; j < 8; ++j)
                    s[j] = __builtin_amdgcn_readlane(eid, fe + j);
#pragma unroll
                for (int j = 0; j < 8; ++j)
                    if (j < rem) v[j] = *(const unsigned short*)&hb[(size_t)s[j] * 128 + c2];
#pragma unroll
                for (int j = 0; j < 8; ++j)
                    if (j < rem) w[j] = __expf(lrelu(aS[s[j]] + adh));
#pragma unroll
                for (int j = 0; j < 8; ++j) {
                    if (j < rem) {
                        den += w[j];
                        f32x2 lo = __builtin_amdgcn_cvt_pk_f32_fp8((int)v[j], false);
                        ax += lo[0] * w[j];
                        ay += lo[1] * w[j];
                    }
                }
            }
        }
        float inv = 1.f / (den + 1e-16f);
        float2 bb = *(const float2*)&b2[c2];
        float v0 = ax * inv + bb.x; v0 = v0 > 0.f ? v0 : expm1f(v0);
        float v1 = ay * inv + bb.y; v1 = v1 > 0.f ? v1 : expm1f(v1);
        pv[wave][c2] = v0;
        pv[wave][c2 + 1] = v1;
    }
    __syncthreads();
    if (threadIdx.x < 128) {
        float* myp = parts + (size_t)(blockIdx.x & 31) * 4096;
        int c = threadIdx.x;
        float acc = 0.f;
        int g = -1;
#pragma unroll
        for (int w = 0; w < 4; ++w) {
            int gw = pg[w];
            if (gw < 0) continue;
            float vw = pv[w][c];
            if (gw == g) {
                acc += vw;
            } else {
                if (g >= 0) atomicAdd(&myp[g * 128 + c], acc);
                g = gw;
                acc = vw;
            }
        }
        if (g >= 0) atomicAdd(&myp[g * 128 + c], acc);
    }
}

// fold the 32 partition planes into sums[G*C]
__global__ void reduce_k(const float* __restrict__ parts, float* __restrict__ sums)
{
    int i = blockIdx.x * 256 + threadIdx.x;    // 0..4095
    float acc = 0.f;
#pragma unroll
    for (int p = 0; p < 32; ++p) acc += parts[(size_t)p * 4096 + i];
    sums[i] = acc;
}

__global__ void final_k(const float* __restrict__ sums, const int* __restrict__ batch,
                        const float* __restrict__ lin_w, const float* __restrict__ lin_b,
                        float* __restrict__ out, int Nn, int G, int C, int NC)
{
    __shared__ float inv[64];
    int t = threadIdx.x;
    if (t < G) {
        int lo = 0, hi = Nn;
        while (lo < hi) { int mid = (lo + hi) >> 1; if (batch[mid] < t) lo = mid + 1; else hi = mid; }
        int lb = lo;
        lo = 0; hi = Nn;
        while (lo < hi) { int mid = (lo + hi) >> 1; if (batch[mid] < t + 1) lo = mid + 1; else hi = mid; }
        int cnt = lo - lb;
        inv[t] = 1.f / fmaxf((float)cnt, 1.f);
    }
    __syncthreads();
    if (t < G * NC) {
        int g = t / NC, k = t % NC;
        float acc = 0.f;
        for (int c = 0; c < C; ++c) acc += sums[g * C + c] * lin_w[c * NC + k];
        out[t] = acc * inv[g] + lin_b[k];
    }
}

extern "C" void kernel_launch(void* const* d_in, const int* in_sizes, int n_in,
                              void* d_out, int out_size, void* d_ws, size_t ws_size,
                              hipStream_t stream)
{
    const float* x      = (const float*)d_in[0];
    const int*   eidx   = (const int*)d_in[1];
    const int*   batch  = (const int*)d_in[2];
    const float* W1     = (const float*)d_in[3];
    const float* att_s1 = (const float*)d_in[4];
    const float* att_d1 = (const float*)d_in[5];
    const float* b1     = (const float*)d_in[6];
    const float* W2     = (const float*)d_in[7];
    const float* att_s2 = (const float*)d_in[8];
    const float* att_d2 = (const float*)d_in[9];
    const float* b2     = (const float*)d_in[10];
    const float* lin_w  = (const float*)d_in[11];
    const float* lin_b  = (const float*)d_in[12];

    const int Nn  = in_sizes[2];         // 50000
    const int E   = in_sizes[1] / 2;     // 800000
    const int H1_ = 4, C1_ = 64, C2_ = 128, G = 32, NC = 5;
    const int D1 = H1_ * C1_;            // 256
    const int ET = E + Nn;
    const int NBUCK = (Nn + 63) >> 6;    // 782 coarse buckets

    const int* srcp = eidx;
    const int* dstp = eidx + E;

    float* ws = (float*)d_ws;
    size_t off = 0;
    auto alloc = [&](size_t n) { float* p = ws + off; off += n; return p; };
    _Float16* o1h = (_Float16*)alloc((size_t)Nn * D1 / 2);    // fp16 layer-1 out
    float* aS1  = alloc((size_t)Nn * H1_);
    float* aD1  = alloc((size_t)Nn * H1_);
    float* aS2  = alloc(Nn);
    float* aD2  = alloc(Nn);
    float* sums = alloc((size_t)G * C2_);
    float* parts = alloc((size_t)32 * G * C2_);               // 32 partitions
    _Float16* BT1 = (_Float16*)alloc(D1 * 128 / 2);           // [256][128] fp16
    _Float16* BT2 = (_Float16*)alloc(C2_ * 256 / 2);          // [128][256] fp16
    unsigned char* hb1 = (unsigned char*)alloc((size_t)Nn * D1 / 4);   // fp8 h1
    unsigned char* hb2 = (unsigned char*)alloc((size_t)Nn * C2_ / 4);  // fp8 h2
    int* iws    = (int*)(ws + off);
    int* rowptr = iws;                               // Nn+1
    int* bcnt   = iws + Nn + 1;                      // 1024
    int* bbase  = iws + Nn + 1 + 1024;               // 1025
    int* ccursor= iws + Nn + 1 + 2049;               // 1024
    unsigned int* tmp = (unsigned int*)(iws + Nn + 1 + 2049 + 1024);   // ET
    unsigned short* esrc = (unsigned short*)(tmp + ET);                // ET u16

    const int GB = (Nn + 63) / 64;
    const int NW = (Nn + 3) / 4;
    const int BINB = (ET + 256 * BIN_EPT - 1) / (256 * BIN_EPT);

    // ---------------- CSR build (two-phase, LDS-aggregated, no global count) ----
    hipMemsetAsync(bcnt, 0, 1024 * 4, stream);
    hipMemsetAsync(parts, 0, (size_t)32 * G * C2_ * 4, stream);
    bcount_k<<<BINB, 256, 0, stream>>>(dstp, bcnt, ET, E, NBUCK);
    bscan_k<<<1, 1024, 0, stream>>>(bcnt, bbase, ccursor, NBUCK);
    binpass_k<<<BINB, 256, 0, stream>>>(srcp, dstp, ccursor, tmp, ET, E, NBUCK);
    fine_k<<<NBUCK, 256, 0, stream>>>(bbase, tmp, rowptr, esrc, Nn, ET, NBUCK);

    // ---------------- weight transpose+convert (fp16) ----------------
    convW_k<<<256, 256, 0, stream>>>(W1, W2, BT1, BT2);

    // ---------------- layer 1: fp16 GEMM + fp8 out + logits fused ----------------
    gemm_fused<256, 128, 4, false><<<GB, 256, 0, stream>>>(x, BT1, hb1, att_s1, att_d1,
                                                           aS1, aD1, Nn);
    gather1_k<<<NW, 256, 0, stream>>>(rowptr, esrc, hb1, aS1, aD1, b1, o1h, Nn);

    // ---------------- layer 2: fp16 GEMM + fp8 out + logits (LDS-reduced) --------
    gemm_fused<128, 256, 1, true><<<GB, 256, 0, stream>>>(o1h, BT2, hb2, att_s2, att_d2,
                                                          aS2, aD2, Nn);
    // gather2 + bias + ELU + graph-sum fused (o2 never materialized)
    gather2_k<<<NW, 256, 0, stream>>>(rowptr, esrc, hb2, aS2, aD2, b2, batch, parts, Nn);

    // ---------------- partition fold + classifier ----------------
    reduce_k<<<16, 256, 0, stream>>>(parts, sums);
    final_k<<<1, 256, 0, stream>>>(sums, batch, lin_w, lin_b, (float*)d_out, Nn, G, C2_, NC);
}

// Round 12
// 301.596 us; speedup vs baseline: 1.0656x; 1.0656x over previous
//
#include <hip/hip_runtime.h>
#include <math.h>

#define NEG_SLOPE 0.2f

__device__ inline float lrelu(float x) { return x > 0.f ? x : NEG_SLOPE * x; }

typedef __attribute__((ext_vector_type(8))) _Float16 f16x8;
typedef __attribute__((ext_vector_type(4))) float f32x4;
typedef __attribute__((ext_vector_type(2))) float f32x2;
typedef __attribute__((ext_vector_type(4))) _Float16 h16x4;

// Convert W1[K1,N1], W2[K2,N2] fp32 -> BT [N][K] fp16 (transposed)
__global__ void convW_k(const float* __restrict__ W1, const float* __restrict__ W2,
                        _Float16* __restrict__ BT1, _Float16* __restrict__ BT2)
{
    int i = blockIdx.x * blockDim.x + threadIdx.x;   // 65536 total
    if (i < 32768) {
        int n = i >> 7, k = i & 127;                 // K=128, N=256
        BT1[(size_t)n * 128 + k] = (_Float16)W1[(size_t)k * 256 + n];
    } else {
        int idx = i - 32768;
        int n = idx >> 8, k = idx & 255;             // K=256, N=128
        BT2[(size_t)n * 256 + k] = (_Float16)W2[(size_t)k * 128 + n];
    }
}

// ---- Fused fp16 MFMA GEMM + fp8 out + attention logits -----------------------
// C = A[M,K] @ W[K,N] (fp16 compute, fp32 acc); epilogue writes HB (fp8 e4m3)
// and per-row attn logits aS/aD. H=4: direct store head=wave; H=1: cross-wave
// LDS reduction then direct store (no atomics, no pre-zeroed buffers).
template<int N, int K, int H, bool AF16>
__launch_bounds__(256)
__global__ void gemm_fused(const void* __restrict__ A, const _Float16* __restrict__ BT,
                           unsigned char* __restrict__ HB, const float* __restrict__ att_s,
                           const float* __restrict__ att_d, float* __restrict__ aS,
                           float* __restrict__ aD, int M)
{
    constexpr int ITERS = K / 32;
    constexpr int WN = N / 4;
    constexpr int NT = WN / 16;
    constexpr int NCH = (N * 4) / 256;
    __shared__ unsigned short As[64 * 40] __attribute__((aligned(16)));
    __shared__ unsigned short Bs[N * 40] __attribute__((aligned(16)));
    __shared__ float sred[2][4][64];               // H==1 cross-wave logit reduce
    const int t = threadIdx.x;
    const int wave = t >> 6, lane = t & 63;
    const int quad = lane >> 4, l15 = lane & 15;
    const int rowBase = blockIdx.x * 64;

    f32x4 acc[4][NT];
#pragma unroll
    for (int mi = 0; mi < 4; ++mi)
#pragma unroll
        for (int ni = 0; ni < NT; ++ni)
            acc[mi][ni] = (f32x4){0.f, 0.f, 0.f, 0.f};

    const int ar = t >> 2;             // A-stage row 0..63
    const int ak = (t & 3) << 3;       // A-stage k seg 0,8,16,24
    const int bc = (t * NCH) >> 2;     // B-stage column
    const int bks = (t * NCH) & 3;     // B-stage starting chunk

    for (int it = 0; it < ITERS; ++it) {
        // ---- stage A
        {
            int gr = rowBase + ar;
            f16x8 hv;
#pragma unroll
            for (int j = 0; j < 8; ++j) hv[j] = (_Float16)0.f;
            if (gr < M) {
                if constexpr (AF16) {
                    hv = *(const f16x8*)((const _Float16*)A + (size_t)gr * K + it * 32 + ak);
                } else {
                    const float* ap = (const float*)A + (size_t)gr * K + it * 32 + ak;
                    float4 v0 = *(const float4*)ap;
                    float4 v1 = *(const float4*)(ap + 4);
                    hv[0] = (_Float16)v0.x; hv[1] = (_Float16)v0.y;
                    hv[2] = (_Float16)v0.z; hv[3] = (_Float16)v0.w;
                    hv[4] = (_Float16)v1.x; hv[5] = (_Float16)v1.y;
                    hv[6] = (_Float16)v1.z; hv[7] = (_Float16)v1.w;
                }
            }
            *(f16x8*)&As[ar * 40 + ak] = hv;
        }
        // ---- stage B (pre-converted fp16, contiguous copy)
        {
            const _Float16* bp = BT + (size_t)bc * K + it * 32 + bks * 8;
            unsigned short* dp = &Bs[bc * 40 + bks * 8];
#pragma unroll
            for (int j = 0; j < NCH; ++j)
                *(f16x8*)(dp + j * 8) = *(const f16x8*)(bp + j * 8);
        }
        __syncthreads();
        f16x8 af[4], bfr[NT];
#pragma unroll
        for (int mi = 0; mi < 4; ++mi)
            af[mi] = *(const f16x8*)&As[(mi * 16 + l15) * 40 + quad * 8];
#pragma unroll
        for (int ni = 0; ni < NT; ++ni)
            bfr[ni] = *(const f16x8*)&Bs[(wave * WN + ni * 16 + l15) * 40 + quad * 8];
#pragma unroll
        for (int mi = 0; mi < 4; ++mi)
#pragma unroll
            for (int ni = 0; ni < NT; ++ni)
                acc[mi][ni] = __builtin_amdgcn_mfma_f32_16x16x32_f16(
                    af[mi], bfr[ni], acc[mi][ni], 0, 0, 0);
        __syncthreads();
    }
    // ---- epilogue: fp8 store + logits. D layout col=lane&15, row=quad*4+reg
    float asv[NT], adv[NT];
#pragma unroll
    for (int ni = 0; ni < NT; ++ni) {
        int col = wave * WN + ni * 16 + l15;
        asv[ni] = att_s[col];
        adv[ni] = att_d[col];
    }
#pragma unroll
    for (int mi = 0; mi < 4; ++mi) {
#pragma unroll
        for (int r = 0; r < 4; ++r) {
            int row = rowBase + mi * 16 + quad * 4 + r;
            bool ok = row < M;
            float ss = 0.f, sd = 0.f;
#pragma unroll
            for (int ni = 0; ni < NT; ++ni) {
                float v = acc[mi][ni][r];
                ss += v * asv[ni];
                sd += v * adv[ni];
            }
            // fp8 pack: 2 cols per cvt inst (cols are 16 apart -> byte stores)
#pragma unroll
            for (int ni = 0; ni < NT; ni += 2) {
                int pk = __builtin_amdgcn_cvt_pk_fp8_f32(acc[mi][ni][r],
                                                         acc[mi][ni + 1][r], 0, false);
                if (ok) {
                    HB[(size_t)row * N + wave * WN + ni * 16 + l15] =
                        (unsigned char)(pk & 0xff);
                    HB[(size_t)row * N + wave * WN + (ni + 1) * 16 + l15] =
                        (unsigned char)((pk >> 8) & 0xff);
                }
            }
#pragma unroll
            for (int off = 8; off > 0; off >>= 1) {
                ss += __shfl_xor(ss, off);
                sd += __shfl_xor(sd, off);
            }
            if (l15 == 0) {
                if (H == 4) {
                    if (ok) {
                        aS[row * 4 + wave] = ss;
                        aD[row * 4 + wave] = sd;
                    }
                } else {
                    sred[0][wave][mi * 16 + quad * 4 + r] = ss;
                    sred[1][wave][mi * 16 + quad * 4 + r] = sd;
                }
            }
        }
    }
    if (H == 1) {
        __syncthreads();
        if (t < 64) {
            int row = rowBase + t;
            if (row < M) {
                aS[row] = sred[0][0][t] + sred[0][1][t] + sred[0][2][t] + sred[0][3][t];
                aD[row] = sred[1][0][t] + sred[1][1][t] + sred[1][2][t] + sred[1][3][t];
            }
        }
    }
}

// =================== CSR build (two-phase sort, LDS-aggregated) =================
// phase 0: LDS-aggregated bucket counting (782 coarse buckets of 64 nodes).
#define BIN_EPT 32
__launch_bounds__(256)
__global__ void bcount_k(const int* __restrict__ dst, int* __restrict__ bcnt,
                         int ET, int E, int NBUCK)
{
    __shared__ int hist[1024];
    for (int i = threadIdx.x; i < NBUCK; i += 256) hist[i] = 0;
    __syncthreads();
    int e0 = blockIdx.x * (256 * BIN_EPT) + threadIdx.x;
#pragma unroll
    for (int j = 0; j < BIN_EPT; ++j) {
        int e = e0 + j * 256;
        if (e < ET) {
            int d = (e < E) ? dst[e] : (e - E);
            atomicAdd(&hist[d >> 6], 1);
        }
    }
    __syncthreads();
    for (int i = threadIdx.x; i < NBUCK; i += 256) {
        int c = hist[i];
        if (c > 0) atomicAdd(&bcnt[i], c);
    }
}

// phase 0b: single-block scan over buckets -> bucket bases + binpass cursors
__global__ void bscan_k(const int* __restrict__ bcnt, int* __restrict__ bbase,
                        int* __restrict__ ccursor, int nb)
{
    __shared__ int sh[1024];
    int t = threadIdx.x;
    int v = (t < nb) ? bcnt[t] : 0;
    sh[t] = v;
    __syncthreads();
#pragma unroll
    for (int o = 1; o < 1024; o <<= 1) {
        int u = (t >= o) ? sh[t - o] : 0;
        __syncthreads();
        sh[t] += u;
        __syncthreads();
    }
    if (t < nb) {
        int excl = sh[t] - v;
        bbase[t] = excl;
        ccursor[t] = excl;
    }
    if (t == nb - 1) bbase[nb] = sh[t];
}

// phase 1: LDS-aggregated coarse scatter. Each block: 8192 edges, LDS histogram,
// ONE global atomicAdd per (block,bucket), then ranked writes.
// Edge packs fully into u32: src | dst<<16 (both < 65536).
__launch_bounds__(256)
__global__ void binpass_k(const int* __restrict__ src, const int* __restrict__ dst,
                          int* __restrict__ ccursor, unsigned int* __restrict__ tmp,
                          int ET, int E, int NBUCK)
{
    __shared__ int hist[1024];
    for (int i = threadIdx.x; i < NBUCK; i += 256) hist[i] = 0;
    __syncthreads();
    int e0 = blockIdx.x * (256 * BIN_EPT) + threadIdx.x;
    unsigned int ev[BIN_EPT];
    int meta[BIN_EPT];
#pragma unroll
    for (int j = 0; j < BIN_EPT; ++j) {
        int e = e0 + j * 256;
        meta[j] = -1;
        if (e < ET) {
            int s, d;
            if (e < E) { s = src[e]; d = dst[e]; } else { s = e - E; d = s; }
            ev[j] = (unsigned int)s | ((unsigned int)d << 16);
            int b = d >> 6;
            int r = atomicAdd(&hist[b], 1);
            meta[j] = (r << 10) | b;          // rank<8192 (13b) | bucket (10b)
        }
    }
    __syncthreads();
    // reserve global ranges: one atomic per touched bucket per block
    for (int i = threadIdx.x; i < NBUCK; i += 256) {
        int c = hist[i];
        hist[i] = (c > 0) ? atomicAdd(&ccursor[i], c) : 0;
    }
    __syncthreads();
#pragma unroll
    for (int j = 0; j < BIN_EPT; ++j) {
        if (meta[j] >= 0) {
            int b = meta[j] & 1023;
            int r = meta[j] >> 10;
            tmp[hist[b] + r] = ev[j];
        }
    }
}

// phase 2: per-bucket fine placement. Derives per-node counts + rowptr from the
// bucket's own edges (64 LDS counters + LDS scan) -- no global count/scan pass.
__global__ void fine_k(const int* __restrict__ bbase, const unsigned int* __restrict__ tmp,
                       int* __restrict__ rowptr, unsigned short* __restrict__ esrc,
                       int Nn, int ET, int NBUCK)
{
    __shared__ int lcnt[64], lpre[64], lcur[64];
    int t = threadIdx.x;
    int b = blockIdx.x;
    int n0 = b << 6;
    int base = bbase[b];
    int end = bbase[b + 1];
    if (t < 64) lcnt[t] = 0;
    __syncthreads();
    for (int i = base + t; i < end; i += 256)
        atomicAdd(&lcnt[(tmp[i] >> 16) & 63], 1);
    __syncthreads();
    if (t < 64) lpre[t] = lcnt[t];
    __syncthreads();
#pragma unroll
    for (int o = 1; o < 64; o <<= 1) {
        int u = (t < 64 && t >= o) ? lpre[t - o] : 0;
        __syncthreads();
        if (t < 64) lpre[t] += u;
        __syncthreads();
    }
    if (t < 64) {
        int n = n0 + t;
        int excl = lpre[t] - lcnt[t];
        if (n < Nn) {
            rowptr[n] = base + excl;
            lcur[t] = base + excl;
        }
    }
    if (b == NBUCK - 1 && t == 0) rowptr[Nn] = ET;
    __syncthreads();
    for (int i = base + t; i < end; i += 256) {
        unsigned int v = tmp[i];
        int pos = atomicAdd(&lcur[(v >> 16) & 63], 1);
        esrc[pos] = (unsigned short)(v & 0xffffu);
    }
}

// ===== gather layer 1: fp8 h, zero-shift softmax (exp without max pass) ========
// Softmax is shift-invariant; logits are O(10) << 88 so exp(l) is fp32-safe.
// Wave-uniform edge ids via readfirstlane; batched guarded tail (no dup loads).
__global__ void gather1_k(const int* __restrict__ rp, const unsigned short* __restrict__ esrc,
                          const unsigned char* __restrict__ hb, const float* __restrict__ aS,
                          const float* __restrict__ aD, const float* __restrict__ bias,
                          _Float16* __restrict__ out, int Nn)
{
    int d = blockIdx.x * 4 + (threadIdx.x >> 6);
    int lane = threadIdx.x & 63;
    if (d >= Nn) return;
    int c4 = lane << 2;                 // channel base = byte offset (fp8)
    int head = lane >> 4;
    int p0 = __builtin_amdgcn_readfirstlane(rp[d]);
    int p1 = __builtin_amdgcn_readfirstlane(rp[d + 1]);
    float adh = aD[d * 4 + head];
    const float* aSh = aS + head;
    float den = 0.f;
    float ax = 0.f, ay = 0.f, az = 0.f, aw = 0.f;
    int p = p0;
    for (; p + 8 <= p1; p += 8) {
        int s[8];
#pragma unroll
        for (int j = 0; j < 8; ++j) s[j] = __builtin_amdgcn_readfirstlane(esrc[p + j]);
        unsigned int v[8];                 // issue vector loads early
#pragma unroll
        for (int j = 0; j < 8; ++j)
            v[j] = *(const unsigned int*)&hb[(size_t)s[j] * 256 + c4];
        float w[8];
#pragma unroll
        for (int j = 0; j < 8; ++j) w[j] = __expf(lrelu(aSh[s[j] * 4] + adh));
#pragma unroll
        for (int j = 0; j < 8; ++j) {
            den += w[j];
            f32x2 lo = __builtin_amdgcn_cvt_pk_f32_fp8((int)v[j], false);
            f32x2 hi = __builtin_amdgcn_cvt_pk_f32_fp8((int)v[j], true);
            ax += lo[0] * w[j];
            ay += lo[1] * w[j];
            az += hi[0] * w[j];
            aw += hi[1] * w[j];
        }
    }
    int rem = p1 - p;                      // 0..7, wave-uniform
    if (rem > 0) {
        int s[8];
        unsigned int v[8];
        float w[8];
#pragma unroll
        for (int j = 0; j < 8; ++j)
            if (j < rem) s[j] = __builtin_amdgcn_readfirstlane(esrc[p + j]);
#pragma unroll
        for (int j = 0; j < 8; ++j)
            if (j < rem) v[j] = *(const unsigned int*)&hb[(size_t)s[j] * 256 + c4];
#pragma unroll
        for (int j = 0; j < 8; ++j)
            if (j < rem) w[j] = __expf(lrelu(aSh[s[j] * 4] + adh));
#pragma unroll
        for (int j = 0; j < 8; ++j) {
            if (j < rem) {
                den += w[j];
                f32x2 lo = __builtin_amdgcn_cvt_pk_f32_fp8((int)v[j], false);
                f32x2 hi = __builtin_amdgcn_cvt_pk_f32_fp8((int)v[j], true);
                ax += lo[0] * w[j];
                ay += lo[1] * w[j];
                az += hi[0] * w[j];
                aw += hi[1] * w[j];
            }
        }
    }
    float inv = 1.f / (den + 1e-16f);
    float4 b4 = *(const float4*)&bias[c4];
    float rx, ry, rz, rw;
    rx = ax * inv + b4.x; rx = rx > 0.f ? rx : expm1f(rx);
    ry = ay * inv + b4.y; ry = ry > 0.f ? ry : expm1f(ry);
    rz = az * inv + b4.z; rz = rz > 0.f ? rz : expm1f(rz);
    rw = aw * inv + b4.w; rw = rw > 0.f ? rw : expm1f(rw);
    h16x4 r16;
    r16[0] = (_Float16)rx; r16[1] = (_Float16)ry;
    r16[2] = (_Float16)rz; r16[3] = (_Float16)rw;
    *(h16x4*)&out[(size_t)d * 256 + c4] = r16;
}

// ===== gather layer 2 + fused mean-pool into PARTITIONED sums ==================
// Zero-shift softmax gather, bias+ELU in-register, block-level run-length
// accumulate, then atomicAdd into parts[blockIdx&31] -- 32-way partitioning
// cuts per-address dependent-RMW chain depth ~420 -> ~13 (the round-9 lesson).
__global__ void gather2_k(const int* __restrict__ rp, const unsigned short* __restrict__ esrc,
                          const unsigned char* __restrict__ hb, const float* __restrict__ aS,
                          const float* __restrict__ aD, const float* __restrict__ b2,
                          const int* __restrict__ batch, float* __restrict__ parts, int Nn)
{
    __shared__ float pv[4][128];
    __shared__ int pg[4];
    int wave = threadIdx.x >> 6;
    int d = blockIdx.x * 4 + wave;
    int lane = threadIdx.x & 63;
    int c2 = lane << 1;                 // channel base = byte offset (fp8)
    bool valid = d < Nn;
    if (lane == 0) pg[wave] = valid ? batch[d] : -1;
    if (valid) {
        int p0 = __builtin_amdgcn_readfirstlane(rp[d]);
        int p1 = __builtin_amdgcn_readfirstlane(rp[d + 1]);
        float adh = aD[d];
        float den = 0.f;
        float ax = 0.f, ay = 0.f;
        int p = p0;
        for (; p + 8 <= p1; p += 8) {
            int s[8];
#pragma unroll
            for (int j = 0; j < 8; ++j) s[j] = __builtin_amdgcn_readfirstlane(esrc[p + j]);
            unsigned short v[8];               // issue vector loads early
#pragma unroll
            for (int j = 0; j < 8; ++j)
                v[j] = *(const unsigned short*)&hb[(size_t)s[j] * 128 + c2];
            float w[8];
#pragma unroll
            for (int j = 0; j < 8; ++j) w[j] = __expf(lrelu(aS[s[j]] + adh));
#pragma unroll
            for (int j = 0; j < 8; ++j) {
                den += w[j];
                f32x2 lo = __builtin_amdgcn_cvt_pk_f32_fp8((int)v[j], false);
                ax += lo[0] * w[j];
                ay += lo[1] * w[j];
            }
        }
        int rem = p1 - p;                      // 0..7, wave-uniform
        if (rem > 0) {
            int s[8];
            unsigned short v[8];
            float w[8];
#pragma unroll
            for (int j = 0; j < 8; ++j)
                if (j < rem) s[j] = __builtin_amdgcn_readfirstlane(esrc[p + j]);
#pragma unroll
            for (int j = 0; j < 8; ++j)
                if (j < rem) v[j] = *(const unsigned short*)&hb[(size_t)s[j] * 128 + c2];
#pragma unroll
            for (int j = 0; j < 8; ++j)
                if (j < rem) w[j] = __expf(lrelu(aS[s[j]] + adh));
#pragma unroll
            for (int j = 0; j < 8; ++j) {
                if (j < rem) {
                    den += w[j];
                    f32x2 lo = __builtin_amdgcn_cvt_pk_f32_fp8((int)v[j], false);
                    ax += lo[0] * w[j];
                    ay += lo[1] * w[j];
                }
            }
        }
        float inv = 1.f / (den + 1e-16f);
        float2 bb = *(const float2*)&b2[c2];
        float v0 = ax * inv + bb.x; v0 = v0 > 0.f ? v0 : expm1f(v0);
        float v1 = ay * inv + bb.y; v1 = v1 > 0.f ? v1 : expm1f(v1);
        pv[wave][c2] = v0;
        pv[wave][c2 + 1] = v1;
    }
    __syncthreads();
    if (threadIdx.x < 128) {
        float* myp = parts + (size_t)(blockIdx.x & 31) * 4096;
        int c = threadIdx.x;
        float acc = 0.f;
        int g = -1;
#pragma unroll
        for (int w = 0; w < 4; ++w) {
            int gw = pg[w];
            if (gw < 0) continue;
            float vw = pv[w][c];
            if (gw == g) {
                acc += vw;
            } else {
                if (g >= 0) atomicAdd(&myp[g * 128 + c], acc);
                g = gw;
                acc = vw;
            }
        }
        if (g >= 0) atomicAdd(&myp[g * 128 + c], acc);
    }
}

// fold the 32 partition planes into sums[G*C]
__global__ void reduce_k(const float* __restrict__ parts, float* __restrict__ sums)
{
    int i = blockIdx.x * 256 + threadIdx.x;    // 0..4095
    float acc = 0.f;
#pragma unroll
    for (int p = 0; p < 32; ++p) acc += parts[(size_t)p * 4096 + i];
    sums[i] = acc;
}

__global__ void final_k(const float* __restrict__ sums, const int* __restrict__ batch,
                        const float* __restrict__ lin_w, const float* __restrict__ lin_b,
                        float* __restrict__ out, int Nn, int G, int C, int NC)
{
    __shared__ float inv[64];
    int t = threadIdx.x;
    if (t < G) {
        int lo = 0, hi = Nn;
        while (lo < hi) { int mid = (lo + hi) >> 1; if (batch[mid] < t) lo = mid + 1; else hi = mid; }
        int lb = lo;
        lo = 0; hi = Nn;
        while (lo < hi) { int mid = (lo + hi) >> 1; if (batch[mid] < t + 1) lo = mid + 1; else hi = mid; }
        int cnt = lo - lb;
        inv[t] = 1.f / fmaxf((float)cnt, 1.f);
    }
    __syncthreads();
    if (t < G * NC) {
        int g = t / NC, k = t % NC;
        float acc = 0.f;
        for (int c = 0; c < C; ++c) acc += sums[g * C + c] * lin_w[c * NC + k];
        out[t] = acc * inv[g] + lin_b[k];
    }
}

extern "C" void kernel_launch(void* const* d_in, const int* in_sizes, int n_in,
                              void* d_out, int out_size, void* d_ws, size_t ws_size,
                              hipStream_t stream)
{
    const float* x      = (const float*)d_in[0];
    const int*   eidx   = (const int*)d_in[1];
    const int*   batch  = (const int*)d_in[2];
    const float* W1     = (const float*)d_in[3];
    const float* att_s1 = (const float*)d_in[4];
    const float* att_d1 = (const float*)d_in[5];
    const float* b1     = (const float*)d_in[6];
    const float* W2     = (const float*)d_in[7];
    const float* att_s2 = (const float*)d_in[8];
    const float* att_d2 = (const float*)d_in[9];
    const float* b2     = (const float*)d_in[10];
    const float* lin_w  = (const float*)d_in[11];
    const float* lin_b  = (const float*)d_in[12];

    const int Nn  = in_sizes[2];         // 50000
    const int E   = in_sizes[1] / 2;     // 800000
    const int H1_ = 4, C1_ = 64, C2_ = 128, G = 32, NC = 5;
    const int D1 = H1_ * C1_;            // 256
    const int ET = E + Nn;
    const int NBUCK = (Nn + 63) >> 6;    // 782 coarse buckets

    const int* srcp = eidx;
    const int* dstp = eidx + E;

    float* ws = (float*)d_ws;
    size_t off = 0;
    auto alloc = [&](size_t n) { float* p = ws + off; off += n; return p; };
    _Float16* o1h = (_Float16*)alloc((size_t)Nn * D1 / 2);    // fp16 layer-1 out
    float* aS1  = alloc((size_t)Nn * H1_);
    float* aD1  = alloc((size_t)Nn * H1_);
    float* aS2  = alloc(Nn);
    float* aD2  = alloc(Nn);
    float* sums = alloc((size_t)G * C2_);
    float* parts = alloc((size_t)32 * G * C2_);               // 32 partitions
    _Float16* BT1 = (_Float16*)alloc(D1 * 128 / 2);           // [256][128] fp16
    _Float16* BT2 = (_Float16*)alloc(C2_ * 256 / 2);          // [128][256] fp16
    unsigned char* hb1 = (unsigned char*)alloc((size_t)Nn * D1 / 4);   // fp8 h1
    unsigned char* hb2 = (unsigned char*)alloc((size_t)Nn * C2_ / 4);  // fp8 h2
    int* iws    = (int*)(ws + off);
    int* rowptr = iws;                               // Nn+1
    int* bcnt   = iws + Nn + 1;                      // 1024
    int* bbase  = iws + Nn + 1 + 1024;               // 1025
    int* ccursor= iws + Nn + 1 + 2049;               // 1024
    unsigned int* tmp = (unsigned int*)(iws + Nn + 1 + 2049 + 1024);   // ET
    unsigned short* esrc = (unsigned short*)(tmp + ET);                // ET u16

    const int GB = (Nn + 63) / 64;
    const int NW = (Nn + 3) / 4;
    const int BINB = (ET + 256 * BIN_EPT - 1) / (256 * BIN_EPT);

    // ---------------- CSR build (two-phase, LDS-aggregated, no global count) ----
    hipMemsetAsync(bcnt, 0, 1024 * 4, stream);
    hipMemsetAsync(parts, 0, (size_t)32 * G * C2_ * 4, stream);
    bcount_k<<<BINB, 256, 0, stream>>>(dstp, bcnt, ET, E, NBUCK);
    bscan_k<<<1, 1024, 0, stream>>>(bcnt, bbase, ccursor, NBUCK);
    binpass_k<<<BINB, 256, 0, stream>>>(srcp, dstp, ccursor, tmp, ET, E, NBUCK);
    fine_k<<<NBUCK, 256, 0, stream>>>(bbase, tmp, rowptr, esrc, Nn, ET, NBUCK);

    // ---------------- weight transpose+convert (fp16) ----------------
    convW_k<<<256, 256, 0, stream>>>(W1, W2, BT1, BT2);

    // ---------------- layer 1: fp16 GEMM + fp8 out + logits fused ----------------
    gemm_fused<256, 128, 4, false><<<GB, 256, 0, stream>>>(x, BT1, hb1, att_s1, att_d1,
                                                           aS1, aD1, Nn);
    gather1_k<<<NW, 256, 0, stream>>>(rowptr, esrc, hb1, aS1, aD1, b1, o1h, Nn);

    // ---------------- layer 2: fp16 GEMM + fp8 out + logits (LDS-reduced) --------
    gemm_fused<128, 256, 1, true><<<GB, 256, 0, stream>>>(o1h, BT2, hb2, att_s2, att_d2,
                                                          aS2, aD2, Nn);
    // gather2 + bias + ELU + graph-sum fused (o2 never materialized)
    gather2_k<<<NW, 256, 0, stream>>>(rowptr, esrc, hb2, aS2, aD2, b2, batch, parts, Nn);

    // ---------------- partition fold + classifier ----------------
    reduce_k<<<16, 256, 0, stream>>>(parts, sums);
    final_k<<<1, 256, 0, stream>>>(sums, batch, lin_w, lin_b, (float*)d_out, Nn, G, C2_, NC);
}